// Round 15
// baseline (2883.916 us; speedup 1.0000x reference)
//
#include <hip/hip_runtime.h>
#include <math.h>

#define H 300
#define H3 900
#define NAt 16385
#define NBd 65537
#define NM 256
#define APM 64

typedef __attribute__((ext_vector_type(8))) short bf16x8;
typedef __attribute__((ext_vector_type(4))) float f32x4;

__device__ __forceinline__ unsigned bf16_rne(float x) {
  unsigned u = __float_as_uint(x);
  return (u + 0x7fffu + ((u >> 16) & 1u)) >> 16;
}
__device__ __forceinline__ float bf16_up(unsigned h) {
  return __uint_as_float(h << 16);
}
// 3-way split: x ~= h + m + l (each bf16), residual ~2^-26 |x|
__device__ __forceinline__ void split3(float x, unsigned &h, unsigned &m, unsigned &l) {
  h = bf16_rne(x);
  float r1 = x - bf16_up(h);
  m = bf16_rne(r1);
  float r2 = r1 - bf16_up(m);
  l = bf16_rne(r2);
}
__device__ __forceinline__ void pack8(const unsigned* v, uint4 &o) {
  o.x = v[0] | (v[1] << 16); o.y = v[2] | (v[3] << 16);
  o.z = v[4] | (v[5] << 16); o.w = v[6] | (v[7] << 16);
}

// ======================= weight pre-split =======================
template<bool TRANS>
__global__ __launch_bounds__(256) void prep_split_kernel(
    const float* __restrict__ B, uint4* __restrict__ out,
    int K, int N, int ldb, int KT, int NT)
{
  int g = blockIdx.x * 256 + threadIdx.x;
  int total = KT * NT * 64;
  if (g >= total) return;
  int lane = g & 63;
  int t = (g >> 6) % NT;
  int kt = (g >> 6) / NT;
  int n = t * 16 + (lane & 15);
  int kb = kt * 32 + ((lane >> 4) << 3);
  float x[8];
#pragma unroll
  for (int j = 0; j < 8; j++) {
    int gk = kb + j;
    float v = 0.f;
    if (n < N && gk < K)
      v = TRANS ? B[(size_t)n * ldb + gk] : B[(size_t)gk * ldb + n];
    x[j] = v;
  }
  unsigned h[8], m[8], l[8];
#pragma unroll
  for (int j = 0; j < 8; j++) split3(x[j], h[j], m[j], l[j]);
  uint4 hv, mv, lv;
  pack8(h, hv); pack8(m, mv); pack8(l, lv);
  out[g] = hv;
  out[total + g] = mv;
  out[2 * total + g] = lv;
}

// ======= w_hh quad-pack Wq[kq][g][j] = W[g][4kq+j] for float4 GRU loads =======
__global__ __launch_bounds__(256) void prep_wq_kernel(
    const float* __restrict__ w, float* __restrict__ wq)
{
  int gid = blockIdx.x * 256 + threadIdx.x;
  if (gid >= H * H3) return;
  int q4 = gid >> 2;
  int j = gid & 3;
  int kq = q4 / H3;
  int g = q4 - kq * H3;
  wq[gid] = w[(size_t)g * H + kq * 4 + j];
}

// ============== split-bf16 MFMA GEMM (EXACT r12 — proven) ==============
template<bool ADDMAT, bool BIAS, bool RELU, bool GATHER, bool CONCAT, bool W2, bool VEC>
__global__ __launch_bounds__(256, 2) void gemm_mfma3(
    const float* __restrict__ A, const float* __restrict__ A2,
    const float* __restrict__ A3,
    const int* __restrict__ idx1, const int* __restrict__ idx2,
    const uint4* __restrict__ Bs,
    float* __restrict__ C, float* __restrict__ C2,
    const float* __restrict__ D, const float* __restrict__ bias,
    int M, int N, int K, int lda, int ldc, int KT, int NT)
{
  __shared__ uint4 sA[2][3][256];
  const int tid = threadIdx.x;
  const int lane = tid & 63;
  const int wid = tid >> 6;
  const int m0 = blockIdx.y * 64;
  const int tb = blockIdx.x * 19;
  const bool J5 = (wid < 3);  // wave-uniform: does this wave own a 5th tile?

  const int a_row = m0 + (wid << 4) + (lane & 15);
  const int a_koct = lane >> 4;
  const bool arok = a_row < M;
  const float* Ap = nullptr;
  const float* Ap2 = nullptr;
  const float* Ap3 = nullptr;
  if constexpr (GATHER) {
    int i1 = arok ? idx1[a_row] : 0;
    int i2 = arok ? idx2[a_row] : 0;
    Ap  = A  + (size_t)i1 * lda;
    Ap2 = A2 + (size_t)i2 * lda;
  } else if constexpr (CONCAT) {
    int r = arok ? a_row : 0;
    Ap  = A  + (size_t)r * lda;
    Ap2 = A2 + (size_t)r * lda;
    Ap3 = A3 + (size_t)r * lda;
  } else {
    Ap = A + (size_t)(arok ? a_row : 0) * lda;
  }

  const int PS = KT * NT * 64;  // plane stride (uint4 units)

  f32x4 acc[4][5];
#pragma unroll
  for (int i = 0; i < 4; i++)
#pragma unroll
    for (int j = 0; j < 5; j++) acc[i][j] = (f32x4){0.f, 0.f, 0.f, 0.f};

  float ax[8];
  auto loadA = [&](int kt_) {
    const int gk0 = (kt_ << 5) + (a_koct << 3);
    if constexpr (VEC && !CONCAT) {
      if (arok && gk0 + 8 <= K) {
        float4 p0 = *(const float4*)(Ap + gk0);
        float4 p1 = *(const float4*)(Ap + gk0 + 4);
        if constexpr (GATHER) {
          float4 q0 = *(const float4*)(Ap2 + gk0);
          float4 q1 = *(const float4*)(Ap2 + gk0 + 4);
          ax[0] = p0.x - q0.x; ax[1] = p0.y - q0.y;
          ax[2] = p0.z - q0.z; ax[3] = p0.w - q0.w;
          ax[4] = p1.x - q1.x; ax[5] = p1.y - q1.y;
          ax[6] = p1.z - q1.z; ax[7] = p1.w - q1.w;
        } else {
          ax[0] = p0.x; ax[1] = p0.y; ax[2] = p0.z; ax[3] = p0.w;
          ax[4] = p1.x; ax[5] = p1.y; ax[6] = p1.z; ax[7] = p1.w;
        }
        return;
      }
    }
#pragma unroll
    for (int j = 0; j < 8; j++) {
      int gk = gk0 + j;
      float v = 0.f;
      if (arok && gk < K) {
        if constexpr (GATHER) {
          v = Ap[gk] - Ap2[gk];
        } else if constexpr (CONCAT) {
          int s_ = (gk >= 2 * lda) ? 2 : ((gk >= lda) ? 1 : 0);
          int col = gk - s_ * lda;
          const float* src = (s_ == 0) ? Ap : ((s_ == 1) ? Ap2 : Ap3);
          v = src[col];
        } else {
          v = Ap[gk];
        }
      }
      ax[j] = v;
    }
  };
  auto writeA = [&](int slot) {
    unsigned h[8], m[8], l[8];
#pragma unroll
    for (int j = 0; j < 8; j++) split3(ax[j], h[j], m[j], l[j]);
    uint4 hv, mv, lv;
    pack8(h, hv); pack8(m, mv); pack8(l, lv);
    const int fi = (wid << 6) | lane;
    sA[slot][0][fi] = hv; sA[slot][1][fi] = mv; sA[slot][2][fi] = lv;
  };

  loadA(0);
  writeA(0);
  __syncthreads();

  for (int kt = 0; kt < KT; kt++) {
    const int cur = kt & 1;
    const bool more = kt + 1 < KT;

    const int bk = kt * NT * 64 + tb * 64 + lane;
    bf16x8 breg[5][3];
#pragma unroll
    for (int j = 0; j < 4; j++) {
      const int gidx = bk + (((j << 2) + wid) << 6);
#pragma unroll
      for (int p = 0; p < 3; p++)
        breg[j][p] = ((const bf16x8*)Bs)[gidx + p * PS];
    }
    if (J5) {
      const int gidx = bk + ((16 + wid) << 6);
#pragma unroll
      for (int p = 0; p < 3; p++)
        breg[4][p] = ((const bf16x8*)Bs)[gidx + p * PS];
    }

    if (more) loadA(kt + 1);

    bf16x8 aF[3][4];
#pragma unroll
    for (int p = 0; p < 3; p++)
#pragma unroll
      for (int i = 0; i < 4; i++)
        aF[p][i] = ((const bf16x8*)sA[cur][p])[(i << 6) | lane];

#pragma unroll
    for (int j = 0; j < 5; j++) {
      if (j < 4 || J5) {
#pragma unroll
        for (int i = 0; i < 4; i++) {
          acc[i][j] = __builtin_amdgcn_mfma_f32_16x16x32_bf16(aF[2][i], breg[j][0], acc[i][j], 0, 0, 0);
          acc[i][j] = __builtin_amdgcn_mfma_f32_16x16x32_bf16(aF[0][i], breg[j][2], acc[i][j], 0, 0, 0);
          acc[i][j] = __builtin_amdgcn_mfma_f32_16x16x32_bf16(aF[1][i], breg[j][1], acc[i][j], 0, 0, 0);
          acc[i][j] = __builtin_amdgcn_mfma_f32_16x16x32_bf16(aF[1][i], breg[j][0], acc[i][j], 0, 0, 0);
          acc[i][j] = __builtin_amdgcn_mfma_f32_16x16x32_bf16(aF[0][i], breg[j][1], acc[i][j], 0, 0, 0);
          acc[i][j] = __builtin_amdgcn_mfma_f32_16x16x32_bf16(aF[0][i], breg[j][0], acc[i][j], 0, 0, 0);
        }
      }
    }
    if (more) writeA(cur ^ 1);
    __syncthreads();
  }

  // epilogue: C/D layout col=lane&15, row=(lane>>4)*4+r ; tile t = 4j + wid
  const int cr = (lane >> 4) << 2;
  const int cc = lane & 15;
#pragma unroll
  for (int j = 0; j < 5; j++) {
    if (j == 4 && !J5) break;
    const int t = (j << 2) + wid;
    const int gn = ((tb + t) << 4) + cc;
    if (gn >= N) continue;
#pragma unroll
    for (int i = 0; i < 4; i++) {
#pragma unroll
      for (int r = 0; r < 4; r++) {
        const int gm = m0 + (i << 4) + cr + r;
        if (gm >= M) continue;
        const size_t rowoff = (size_t)gm * ldc;
        float v = acc[i][j][r];
        if constexpr (ADDMAT) v += D[rowoff + gn];
        if constexpr (BIAS) v += bias[gn];
        if constexpr (RELU) v = fmaxf(v, 0.f);
        C[rowoff + gn] = v;
        if constexpr (W2) C2[rowoff + gn] = v;
      }
    }
  }
}

// ============== neighbor aggregation (float4): sum * max over 6 ==============
template<bool UPDATE>
__global__ __launch_bounds__(256) void agg_kernel(
    const float* __restrict__ message_bond, const int* __restrict__ a2b,
    float* __restrict__ out)
{
  int gid = blockIdx.x * 256 + threadIdx.x;
  if (gid >= NAt * 75) return;
  int a = gid / 75;
  int c4 = gid - a * 75;
  const int* ab = a2b + (size_t)a * 6;
  float4 s = {0.f, 0.f, 0.f, 0.f};
  float4 mx = {-3.0e38f, -3.0e38f, -3.0e38f, -3.0e38f};
#pragma unroll
  for (int j = 0; j < 6; j++) {
    float4 v = *(const float4*)(message_bond + (size_t)ab[j] * H + c4 * 4);
    s.x += v.x; s.y += v.y; s.z += v.z; s.w += v.w;
    mx.x = fmaxf(mx.x, v.x); mx.y = fmaxf(mx.y, v.y);
    mx.z = fmaxf(mx.z, v.z); mx.w = fmaxf(mx.w, v.w);
  }
  float4* o = (float4*)(out + (size_t)a * H + c4 * 4);
  float4 r;
  r.x = s.x * mx.x; r.y = s.y * mx.y; r.z = s.z * mx.z; r.w = s.w * mx.w;
  if (UPDATE) {
    float4 c = *o;
    r.x += c.x; r.y += c.y; r.z += c.z; r.w += c.w;
  }
  *o = r;
}

// ======================= misc elementwise =======================
__global__ __launch_bounds__(256) void msg_kernel(
    const float* __restrict__ node, const float* __restrict__ gru_bias,
    float* __restrict__ msg)
{
  int gid = blockIdx.x * 256 + threadIdx.x;
  if (gid >= NAt * H) return;
  int hh = gid % H;
  msg[gid] = fmaxf(node[gid] + gru_bias[hh], 0.f);
}

__global__ __launch_bounds__(256) void h0_kernel(
    const float* __restrict__ node, float* __restrict__ h0)
{
  int gid = blockIdx.x * 256 + threadIdx.x;
  if (gid >= NM * H) return;
  int m = gid / H;
  int hh = gid - m * H;
  const float* base = node + ((size_t)(1 + m * APM)) * H + hh;
  float mx = base[0];
  for (int t = 1; t < APM; t++) mx = fmaxf(mx, base[(size_t)t * H]);
  h0[gid] = mx;
}

__global__ __launch_bounds__(256) void row0_kernel(
    const float* __restrict__ msg, float* __restrict__ message)
{
  int gid = blockIdx.x * 256 + threadIdx.x;
  if (gid >= 2 * H) return;
  message[gid] = msg[gid % H];
}

__global__ __launch_bounds__(256) void mean_kernel(
    const float* __restrict__ ah, float* __restrict__ out)
{
  int gid = blockIdx.x * 256 + threadIdx.x;
  if (gid >= NM * H) return;
  int m = gid / H;
  int hh = gid - m * H;
  const float* base = ah + ((size_t)(1 + m * APM)) * H + hh;
  float s = 0.f;
#pragma unroll 8
  for (int t = 0; t < APM; t++) s += base[(size_t)t * H];
  out[gid] = s * (1.f / APM);
}

// ======================= GRU: block-independent, all 65 steps, ONE launch =======================
// r24 = r23 (proven 786us) with phase-2 at 4 GATES/thread:
//   225 threads own gates (t, t+225, t+450, t+675) x 2 mols = 8 accs.
//   Per chunk: 12 W-quads + 6 h-quads SHARED by 4 gates -> 16 FMA per
//   h-read (r23: 8). Block LDS h-read instrs halve again: 67.5k -> 33.75k
//   per step (~3us/step). W-L2 traffic unchanged (irreducible here).
//   Regs ~100 (12W+6h quads + 8 accs) - no spill at 512 thr (<256 cap).
// Per-gate 25-chunk FP ladder identical to r18/r22/r23 -> same output.
// Bias loads hoisted out of the step loop (step-invariant).
__global__ __launch_bounds__(512) void gru_fused_kernel(
    const float* __restrict__ xg_f, const float* __restrict__ xg_b,
    const float* __restrict__ wq_f, const float* __restrict__ wq_b,
    const float* __restrict__ b_hh_f, const float* __restrict__ b_hh_b,
    const float* __restrict__ h0,
    float* __restrict__ message) // [NAt][600]
{
  __shared__ __attribute__((aligned(16))) float h_lds[2][2 * H];
  __shared__ __attribute__((aligned(16))) float g_lds[2 * H3];
  const int tid = threadIdx.x;
  const int b = blockIdx.x;
  const int mg = b & 127;
  const int dir = b >> 7;
  const int mol0 = mg * 2;
  const float* xg = dir ? xg_b : xg_f;
  const float4* wq = (const float4*)(dir ? wq_b : wq_f);  // [75][900] float4
  const float* bhh = dir ? b_hh_b : b_hh_f;

  float bb0 = 0.f, bb1 = 0.f, bb2 = 0.f, bb3 = 0.f;
  if (tid < 225) {
    bb0 = bhh[tid];
    bb1 = bhh[tid + 225];
    bb2 = bhh[tid + 450];
    bb3 = bhh[tid + 675];
  }

  for (int s = 0; s <= 64; s++) {
    float* hl_w = h_lds[s & 1];
    const float* hl_r = h_lds[(s ^ 1) & 1];
    int t_prev = 0;
    if (s > 0) t_prev = dir ? (64 - s) : (s - 1);

    // phase 1: h(s) for this block's 2 mols; write message row for t_prev
    for (int i = tid; i < 2 * H; i += 512) {
      int m = i / H;
      int hh = i - m * H;
      int mol = mol0 + m;
      float hc;
      if (s == 0) {
        hc = h0[(size_t)mol * H + hh];
      } else {
        const float* xr = xg + ((size_t)(mol * 64 + t_prev)) * H3;
        float ir = xr[hh], iz = xr[H + hh], inn = xr[2 * H + hh];
        const float* gp = g_lds + m * H3;
        float hr = gp[hh], hz = gp[H + hh], hn = gp[2 * H + hh];
        float hp = hl_r[i];
        float rr = 1.f / (1.f + expf(-(ir + hr)));
        float zz = 1.f / (1.f + expf(-(iz + hz)));
        float nn = tanhf(inn + rr * hn);
        hc = (1.f - zz) * nn + zz * hp;
      }
      hl_w[i] = hc;
      if (s > 0) {
        int row = 1 + mol * 64 + t_prev;
        message[(size_t)row * 600 + dir * H + hh] = hc;
      }
    }
    __syncthreads();
    if (s == 64) break;

    // phase 2: thread t (<225) owns gates t, t+225, t+450, t+675; 2 mols each.
    if (tid < 225) {
      const int g0 = tid;
      const int g1 = tid + 225;
      const int g2 = tid + 450;
      const int g3 = tid + 675;
      float a00 = 0.f, a01 = 0.f;  // gate0 x {mol0, mol1}
      float a10 = 0.f, a11 = 0.f;
      float a20 = 0.f, a21 = 0.f;
      float a30 = 0.f, a31 = 0.f;
      const float4* hm0 = (const float4*)(hl_w);
      const float4* hm1 = (const float4*)(hl_w + H);
#pragma unroll 5
      for (int c = 0; c < 25; c++) {
        const size_t r0 = (size_t)(c * 3 + 0) * H3;
        const size_t r1 = (size_t)(c * 3 + 1) * H3;
        const size_t r2 = (size_t)(c * 3 + 2) * H3;
        float4 u0 = wq[r0 + g0], u1 = wq[r1 + g0], u2 = wq[r2 + g0];
        float4 v0 = wq[r0 + g1], v1 = wq[r1 + g1], v2 = wq[r2 + g1];
        float4 w0 = wq[r0 + g2], w1 = wq[r1 + g2], w2 = wq[r2 + g2];
        float4 x0 = wq[r0 + g3], x1 = wq[r1 + g3], x2 = wq[r2 + g3];
        float4 p0 = hm0[c * 3], p1 = hm0[c * 3 + 1], p2 = hm0[c * 3 + 2];
        float4 q0 = hm1[c * 3], q1 = hm1[c * 3 + 1], q2 = hm1[c * 3 + 2];
        a00 += u0.x * p0.x + u0.y * p0.y + u0.z * p0.z + u0.w * p0.w
             + u1.x * p1.x + u1.y * p1.y + u1.z * p1.z + u1.w * p1.w
             + u2.x * p2.x + u2.y * p2.y + u2.z * p2.z + u2.w * p2.w;
        a01 += u0.x * q0.x + u0.y * q0.y + u0.z * q0.z + u0.w * q0.w
             + u1.x * q1.x + u1.y * q1.y + u1.z * q1.z + u1.w * q1.w
             + u2.x * q2.x + u2.y * q2.y + u2.z * q2.z + u2.w * q2.w;
        a10 += v0.x * p0.x + v0.y * p0.y + v0.z * p0.z + v0.w * p0.w
             + v1.x * p1.x + v1.y * p1.y + v1.z * p1.z + v1.w * p1.w
             + v2.x * p2.x + v2.y * p2.y + v2.z * p2.z + v2.w * p2.w;
        a11 += v0.x * q0.x + v0.y * q0.y + v0.z * q0.z + v0.w * q0.w
             + v1.x * q1.x + v1.y * q1.y + v1.z * q1.z + v1.w * q1.w
             + v2.x * q2.x + v2.y * q2.y + v2.z * q2.z + v2.w * q2.w;
        a20 += w0.x * p0.x + w0.y * p0.y + w0.z * p0.z + w0.w * p0.w
             + w1.x * p1.x + w1.y * p1.y + w1.z * p1.z + w1.w * p1.w
             + w2.x * p2.x + w2.y * p2.y + w2.z * p2.z + w2.w * p2.w;
        a21 += w0.x * q0.x + w0.y * q0.y + w0.z * q0.z + w0.w * q0.w
             + w1.x * q1.x + w1.y * q1.y + w1.z * q1.z + w1.w * q1.w
             + w2.x * q2.x + w2.y * q2.y + w2.z * q2.z + w2.w * q2.w;
        a30 += x0.x * p0.x + x0.y * p0.y + x0.z * p0.z + x0.w * p0.w
             + x1.x * p1.x + x1.y * p1.y + x1.z * p1.z + x1.w * p1.w
             + x2.x * p2.x + x2.y * p2.y + x2.z * p2.z + x2.w * p2.w;
        a31 += x0.x * q0.x + x0.y * q0.y + x0.z * q0.z + x0.w * q0.w
             + x1.x * q1.x + x1.y * q1.y + x1.z * q1.z + x1.w * q1.w
             + x2.x * q2.x + x2.y * q2.y + x2.z * q2.z + x2.w * q2.w;
      }
      g_lds[g0] = a00 + bb0;
      g_lds[H3 + g0] = a01 + bb0;
      g_lds[g1] = a10 + bb1;
      g_lds[H3 + g1] = a11 + bb1;
      g_lds[g2] = a20 + bb2;
      g_lds[H3 + g2] = a21 + bb2;
      g_lds[g3] = a30 + bb3;
      g_lds[H3 + g3] = a31 + bb3;
    }
    __syncthreads();
  }
}

// ======================= host =======================
// Base layout 63,898,800 floats = 255.6 MB + pre-split weights 9.2 MB
// + quad-packed w_hh 2.16 MB at tail.
extern "C" void kernel_launch(void* const* d_in, const int* in_sizes, int n_in,
                              void* d_out, int out_size, void* d_ws, size_t ws_size,
                              hipStream_t stream) {
  (void)in_sizes; (void)n_in; (void)out_size; (void)ws_size;
  const float* f_atoms  = (const float*)d_in[0];
  const float* f_bonds  = (const float*)d_in[1];
  const int*   a2b      = (const int*)d_in[2];
  const int*   b2a      = (const int*)d_in[3];
  const int*   b2revb   = (const int*)d_in[4];
  const float* W_i_atom = (const float*)d_in[5];
  const float* W_i_bond = (const float*)d_in[6];
  const float* W_h      = (const float*)d_in[7];
  const float* W_lr     = (const float*)d_in[8];
  const float* W_o      = (const float*)d_in[9];
  const float* b_o      = (const float*)d_in[10];
  const float* gru_bias = (const float*)d_in[11];
  const float* w_ih_f   = (const float*)d_in[12];
  const float* w_hh_f   = (const float*)d_in[13];
  const float* b_ih_f   = (const float*)d_in[14];
  const float* b_hh_f   = (const float*)d_in[15];
  const float* w_ih_b   = (const float*)d_in[16];
  const float* w_hh_b   = (const float*)d_in[17];
  const float* b_ih_b   = (const float*)d_in[18];
  const float* b_hh_b   = (const float*)d_in[19];

  float* ws = (float*)d_ws;
  const size_t SZ_B = (size_t)NBd * H;  // 19,661,100
  const size_t SZ_A = (size_t)NAt * H;  //  4,915,500

  float* ib  = ws;
  float* mb0 = ws + SZ_B;
  float* mb1 = ws + 2 * SZ_B;
  float* ma  = ws + 3 * SZ_B;
  float* xgf     = ib;
  float* message = mb0;
  float* h0      = mb0 + 9831000;
  float* aggb    = mb1;
  float* node    = mb1 + SZ_A;
  float* iat     = mb1 + 2 * SZ_A;
  float* msg     = mb1 + 14745600;
  float* xgb     = mb1;
  float* ah      = ma;

  // pre-split weight region at tail (uint4 granule counts)
  const size_t BASE_FLOATS = 63898800;
  uint4* wsp = (uint4*)(ws + BASE_FLOATS);
  const int G_IA = 5 * 19 * 64;
  const int G_IB = 5 * 19 * 64;
  const int G_WH = 10 * 19 * 64;
  const int G_LR = 29 * 19 * 64;
  const int G_WT = 10 * 57 * 64;
  const int G_WO = 19 * 19 * 64;
  uint4* sp_ia = wsp;
  uint4* sp_ib = sp_ia + 3 * G_IA;
  uint4* sp_wh = sp_ib + 3 * G_IB;
  uint4* sp_lr = sp_wh + 4 * 3 * G_WH;
  uint4* sp_tf = sp_lr + 3 * G_LR;
  uint4* sp_tb = sp_tf + 3 * G_WT;
  uint4* sp_wo = sp_tb + 3 * G_WT;
  // quad-packed w_hh (float) after the split region
  float* wq_f = (float*)(sp_wo + 3 * G_WO);
  float* wq_b = wq_f + (size_t)H * H3;

  dim3 blk(256);
  // all N used here are exact multiples of 19 tiles (300->19, 912->57)
  auto gg3 = [](int M, int NT) {
    return dim3((unsigned)(NT / 19), (unsigned)((M + 63) / 64));
  };
  auto pg = [](int gran) { return dim3((unsigned)((gran + 255) / 256)); };
  const int gA4 = (int)((NAt * 75 + 255) / 256);
  const int gAe = (int)((SZ_A + 255) / 256);
  const int gWT = (int)((H * H3 + 255) / 256);

  // ---- weight prep ----
  prep_split_kernel<false><<<pg(G_IA), blk, 0, stream>>>(W_i_atom, sp_ia, 133, 300, 300, 5, 19);
  prep_split_kernel<false><<<pg(G_IB), blk, 0, stream>>>(W_i_bond, sp_ib, 147, 300, 300, 5, 19);
  for (int d = 0; d < 4; d++)
    prep_split_kernel<false><<<pg(G_WH), blk, 0, stream>>>(
        W_h + (size_t)d * H * H, sp_wh + (size_t)d * 3 * G_WH, 300, 300, 300, 10, 19);
  prep_split_kernel<false><<<pg(G_LR), blk, 0, stream>>>(W_lr, sp_lr, 900, 300, 300, 29, 19);
  prep_split_kernel<true><<<pg(G_WT), blk, 0, stream>>>(w_ih_f, sp_tf, 300, 900, 300, 10, 57);
  prep_split_kernel<true><<<pg(G_WT), blk, 0, stream>>>(w_ih_b, sp_tb, 300, 900, 300, 10, 57);
  prep_split_kernel<false><<<pg(G_WO), blk, 0, stream>>>(W_o, sp_wo, 600, 300, 300, 19, 19);
  prep_wq_kernel<<<gWT, blk, 0, stream>>>(w_hh_f, wq_f);
  prep_wq_kernel<<<gWT, blk, 0, stream>>>(w_hh_b, wq_b);

  // ma = relu(f_atoms @ W_i_atom)
  gemm_mfma3<false,false,true,false,false,false,false><<<gg3(NAt, 19), blk, 0, stream>>>(
      f_atoms, nullptr, nullptr, nullptr, nullptr, sp_ia, ma, nullptr, nullptr, nullptr,
      NAt, H, 133, 133, H, 5, 19);
  // ib = relu(f_bonds @ W_i_bond); mb0 = copy
  gemm_mfma3<false,false,true,false,false,true,false><<<gg3(NBd, 19), blk, 0, stream>>>(
      f_bonds, nullptr, nullptr, nullptr, nullptr, sp_ib, ib, mb0, nullptr, nullptr,
      NBd, H, 147, 147, H, 5, 19);

  float* mbp[2] = {mb0, mb1};
  int cur = 0;
  for (int d = 0; d < 4; d++) {
    agg_kernel<true><<<gA4, blk, 0, stream>>>(mbp[cur], a2b, ma);
    gemm_mfma3<true,false,true,true,false,false,true><<<gg3(NBd, 19), blk, 0, stream>>>(
        ma, mbp[cur], nullptr, b2a, b2revb, sp_wh + (size_t)d * 3 * G_WH,
        mbp[1 - cur], nullptr, ib, nullptr, NBd, H, H, H, H, 10, 19);
    cur ^= 1;
  }
  agg_kernel<false><<<gA4, blk, 0, stream>>>(mb0, a2b, aggb);

  gemm_mfma3<false,false,true,false,false,false,false><<<gg3(NAt, 19), blk, 0, stream>>>(
      f_atoms, nullptr, nullptr, nullptr, nullptr, sp_ia, iat, nullptr, nullptr, nullptr,
      NAt, H, 133, 133, H, 5, 19);
  gemm_mfma3<false,false,false,false,true,false,false><<<gg3(NAt, 19), blk, 0, stream>>>(
      aggb, ma, iat, nullptr, nullptr, sp_lr, node, nullptr, nullptr, nullptr,
      NAt, H, 900, H, H, 29, 19);

  h0_kernel<<<(NM * H + 255) / 256, blk, 0, stream>>>(node, h0);
  msg_kernel<<<gAe, blk, 0, stream>>>(node, gru_bias, msg);

  gemm_mfma3<false,true,false,false,false,false,true><<<gg3(16384, 57), blk, 0, stream>>>(
      msg + H, nullptr, nullptr, nullptr, nullptr, sp_tf, xgf, nullptr, nullptr, b_ih_f,
      16384, H3, H, H, H3, 10, 57);
  gemm_mfma3<false,true,false,false,false,false,true><<<gg3(16384, 57), blk, 0, stream>>>(
      msg + H, nullptr, nullptr, nullptr, nullptr, sp_tb, xgb, nullptr, nullptr, b_ih_b,
      16384, H3, H, H, H3, 10, 57);

  // all 65 GRU steps: one launch, 256 independent blocks, 4 gates/thread
  gru_fused_kernel<<<dim3(256), dim3(512), 0, stream>>>(
      xgf, xgb, wq_f, wq_b, b_hh_f, b_hh_b, h0, message);

  row0_kernel<<<3, blk, 0, stream>>>(msg, message);

  gemm_mfma3<false,true,true,false,false,false,true><<<gg3(NAt, 19), blk, 0, stream>>>(
      message, nullptr, nullptr, nullptr, nullptr, sp_wo, ah, nullptr, nullptr, b_o,
      NAt, H, 600, 600, H, 19, 19);
  mean_kernel<<<(NM * H + 255) / 256, blk, 0, stream>>>(ah, (float*)d_out);
}

// Round 16
// 2005.070 us; speedup vs baseline: 1.4383x; 1.4383x over previous
//
#include <hip/hip_runtime.h>
#include <math.h>

#define H 300
#define H3 900
#define NAt 16385
#define NBd 65537
#define NM 256
#define APM 64

typedef __attribute__((ext_vector_type(8))) short bf16x8;
typedef __attribute__((ext_vector_type(4))) float f32x4;

__device__ __forceinline__ unsigned bf16_rne(float x) {
  unsigned u = __float_as_uint(x);
  return (u + 0x7fffu + ((u >> 16) & 1u)) >> 16;
}
__device__ __forceinline__ float bf16_up(unsigned h) {
  return __uint_as_float(h << 16);
}
// 3-way split: x ~= h + m + l (each bf16), residual ~2^-26 |x|
__device__ __forceinline__ void split3(float x, unsigned &h, unsigned &m, unsigned &l) {
  h = bf16_rne(x);
  float r1 = x - bf16_up(h);
  m = bf16_rne(r1);
  float r2 = r1 - bf16_up(m);
  l = bf16_rne(r2);
}
__device__ __forceinline__ void pack8(const unsigned* v, uint4 &o) {
  o.x = v[0] | (v[1] << 16); o.y = v[2] | (v[3] << 16);
  o.z = v[4] | (v[5] << 16); o.w = v[6] | (v[7] << 16);
}

// ======================= weight pre-split =======================
template<bool TRANS>
__global__ __launch_bounds__(256) void prep_split_kernel(
    const float* __restrict__ B, uint4* __restrict__ out,
    int K, int N, int ldb, int KT, int NT)
{
  int g = blockIdx.x * 256 + threadIdx.x;
  int total = KT * NT * 64;
  if (g >= total) return;
  int lane = g & 63;
  int t = (g >> 6) % NT;
  int kt = (g >> 6) / NT;
  int n = t * 16 + (lane & 15);
  int kb = kt * 32 + ((lane >> 4) << 3);
  float x[8];
#pragma unroll
  for (int j = 0; j < 8; j++) {
    int gk = kb + j;
    float v = 0.f;
    if (n < N && gk < K)
      v = TRANS ? B[(size_t)n * ldb + gk] : B[(size_t)gk * ldb + n];
    x[j] = v;
  }
  unsigned h[8], m[8], l[8];
#pragma unroll
  for (int j = 0; j < 8; j++) split3(x[j], h[j], m[j], l[j]);
  uint4 hv, mv, lv;
  pack8(h, hv); pack8(m, mv); pack8(l, lv);
  out[g] = hv;
  out[total + g] = mv;
  out[2 * total + g] = lv;
}

// ======= w_hh quad-pack Wq[kq][g][j] = W[g][4kq+j] for float4 GRU loads =======
__global__ __launch_bounds__(256) void prep_wq_kernel(
    const float* __restrict__ w, float* __restrict__ wq)
{
  int gid = blockIdx.x * 256 + threadIdx.x;
  if (gid >= H * H3) return;
  int q4 = gid >> 2;
  int j = gid & 3;
  int kq = q4 / H3;
  int g = q4 - kq * H3;
  wq[gid] = w[(size_t)g * H + kq * 4 + j];
}

// ============== split-bf16 MFMA GEMM (EXACT r12 — proven) ==============
template<bool ADDMAT, bool BIAS, bool RELU, bool GATHER, bool CONCAT, bool W2, bool VEC>
__global__ __launch_bounds__(256, 2) void gemm_mfma3(
    const float* __restrict__ A, const float* __restrict__ A2,
    const float* __restrict__ A3,
    const int* __restrict__ idx1, const int* __restrict__ idx2,
    const uint4* __restrict__ Bs,
    float* __restrict__ C, float* __restrict__ C2,
    const float* __restrict__ D, const float* __restrict__ bias,
    int M, int N, int K, int lda, int ldc, int KT, int NT)
{
  __shared__ uint4 sA[2][3][256];
  const int tid = threadIdx.x;
  const int lane = tid & 63;
  const int wid = tid >> 6;
  const int m0 = blockIdx.y * 64;
  const int tb = blockIdx.x * 19;
  const bool J5 = (wid < 3);  // wave-uniform: does this wave own a 5th tile?

  const int a_row = m0 + (wid << 4) + (lane & 15);
  const int a_koct = lane >> 4;
  const bool arok = a_row < M;
  const float* Ap = nullptr;
  const float* Ap2 = nullptr;
  const float* Ap3 = nullptr;
  if constexpr (GATHER) {
    int i1 = arok ? idx1[a_row] : 0;
    int i2 = arok ? idx2[a_row] : 0;
    Ap  = A  + (size_t)i1 * lda;
    Ap2 = A2 + (size_t)i2 * lda;
  } else if constexpr (CONCAT) {
    int r = arok ? a_row : 0;
    Ap  = A  + (size_t)r * lda;
    Ap2 = A2 + (size_t)r * lda;
    Ap3 = A3 + (size_t)r * lda;
  } else {
    Ap = A + (size_t)(arok ? a_row : 0) * lda;
  }

  const int PS = KT * NT * 64;  // plane stride (uint4 units)

  f32x4 acc[4][5];
#pragma unroll
  for (int i = 0; i < 4; i++)
#pragma unroll
    for (int j = 0; j < 5; j++) acc[i][j] = (f32x4){0.f, 0.f, 0.f, 0.f};

  float ax[8];
  auto loadA = [&](int kt_) {
    const int gk0 = (kt_ << 5) + (a_koct << 3);
    if constexpr (VEC && !CONCAT) {
      if (arok && gk0 + 8 <= K) {
        float4 p0 = *(const float4*)(Ap + gk0);
        float4 p1 = *(const float4*)(Ap + gk0 + 4);
        if constexpr (GATHER) {
          float4 q0 = *(const float4*)(Ap2 + gk0);
          float4 q1 = *(const float4*)(Ap2 + gk0 + 4);
          ax[0] = p0.x - q0.x; ax[1] = p0.y - q0.y;
          ax[2] = p0.z - q0.z; ax[3] = p0.w - q0.w;
          ax[4] = p1.x - q1.x; ax[5] = p1.y - q1.y;
          ax[6] = p1.z - q1.z; ax[7] = p1.w - q1.w;
        } else {
          ax[0] = p0.x; ax[1] = p0.y; ax[2] = p0.z; ax[3] = p0.w;
          ax[4] = p1.x; ax[5] = p1.y; ax[6] = p1.z; ax[7] = p1.w;
        }
        return;
      }
    }
#pragma unroll
    for (int j = 0; j < 8; j++) {
      int gk = gk0 + j;
      float v = 0.f;
      if (arok && gk < K) {
        if constexpr (GATHER) {
          v = Ap[gk] - Ap2[gk];
        } else if constexpr (CONCAT) {
          int s_ = (gk >= 2 * lda) ? 2 : ((gk >= lda) ? 1 : 0);
          int col = gk - s_ * lda;
          const float* src = (s_ == 0) ? Ap : ((s_ == 1) ? Ap2 : Ap3);
          v = src[col];
        } else {
          v = Ap[gk];
        }
      }
      ax[j] = v;
    }
  };
  auto writeA = [&](int slot) {
    unsigned h[8], m[8], l[8];
#pragma unroll
    for (int j = 0; j < 8; j++) split3(ax[j], h[j], m[j], l[j]);
    uint4 hv, mv, lv;
    pack8(h, hv); pack8(m, mv); pack8(l, lv);
    const int fi = (wid << 6) | lane;
    sA[slot][0][fi] = hv; sA[slot][1][fi] = mv; sA[slot][2][fi] = lv;
  };

  loadA(0);
  writeA(0);
  __syncthreads();

  for (int kt = 0; kt < KT; kt++) {
    const int cur = kt & 1;
    const bool more = kt + 1 < KT;

    const int bk = kt * NT * 64 + tb * 64 + lane;
    bf16x8 breg[5][3];
#pragma unroll
    for (int j = 0; j < 4; j++) {
      const int gidx = bk + (((j << 2) + wid) << 6);
#pragma unroll
      for (int p = 0; p < 3; p++)
        breg[j][p] = ((const bf16x8*)Bs)[gidx + p * PS];
    }
    if (J5) {
      const int gidx = bk + ((16 + wid) << 6);
#pragma unroll
      for (int p = 0; p < 3; p++)
        breg[4][p] = ((const bf16x8*)Bs)[gidx + p * PS];
    }

    if (more) loadA(kt + 1);

    bf16x8 aF[3][4];
#pragma unroll
    for (int p = 0; p < 3; p++)
#pragma unroll
      for (int i = 0; i < 4; i++)
        aF[p][i] = ((const bf16x8*)sA[cur][p])[(i << 6) | lane];

#pragma unroll
    for (int j = 0; j < 5; j++) {
      if (j < 4 || J5) {
#pragma unroll
        for (int i = 0; i < 4; i++) {
          acc[i][j] = __builtin_amdgcn_mfma_f32_16x16x32_bf16(aF[2][i], breg[j][0], acc[i][j], 0, 0, 0);
          acc[i][j] = __builtin_amdgcn_mfma_f32_16x16x32_bf16(aF[0][i], breg[j][2], acc[i][j], 0, 0, 0);
          acc[i][j] = __builtin_amdgcn_mfma_f32_16x16x32_bf16(aF[1][i], breg[j][1], acc[i][j], 0, 0, 0);
          acc[i][j] = __builtin_amdgcn_mfma_f32_16x16x32_bf16(aF[1][i], breg[j][0], acc[i][j], 0, 0, 0);
          acc[i][j] = __builtin_amdgcn_mfma_f32_16x16x32_bf16(aF[0][i], breg[j][1], acc[i][j], 0, 0, 0);
          acc[i][j] = __builtin_amdgcn_mfma_f32_16x16x32_bf16(aF[0][i], breg[j][0], acc[i][j], 0, 0, 0);
        }
      }
    }
    if (more) writeA(cur ^ 1);
    __syncthreads();
  }

  // epilogue: C/D layout col=lane&15, row=(lane>>4)*4+r ; tile t = 4j + wid
  const int cr = (lane >> 4) << 2;
  const int cc = lane & 15;
#pragma unroll
  for (int j = 0; j < 5; j++) {
    if (j == 4 && !J5) break;
    const int t = (j << 2) + wid;
    const int gn = ((tb + t) << 4) + cc;
    if (gn >= N) continue;
#pragma unroll
    for (int i = 0; i < 4; i++) {
#pragma unroll
      for (int r = 0; r < 4; r++) {
        const int gm = m0 + (i << 4) + cr + r;
        if (gm >= M) continue;
        const size_t rowoff = (size_t)gm * ldc;
        float v = acc[i][j][r];
        if constexpr (ADDMAT) v += D[rowoff + gn];
        if constexpr (BIAS) v += bias[gn];
        if constexpr (RELU) v = fmaxf(v, 0.f);
        C[rowoff + gn] = v;
        if constexpr (W2) C2[rowoff + gn] = v;
      }
    }
  }
}

// ============== neighbor aggregation (float4): sum * max over 6 ==============
template<bool UPDATE>
__global__ __launch_bounds__(256) void agg_kernel(
    const float* __restrict__ message_bond, const int* __restrict__ a2b,
    float* __restrict__ out)
{
  int gid = blockIdx.x * 256 + threadIdx.x;
  if (gid >= NAt * 75) return;
  int a = gid / 75;
  int c4 = gid - a * 75;
  const int* ab = a2b + (size_t)a * 6;
  float4 s = {0.f, 0.f, 0.f, 0.f};
  float4 mx = {-3.0e38f, -3.0e38f, -3.0e38f, -3.0e38f};
#pragma unroll
  for (int j = 0; j < 6; j++) {
    float4 v = *(const float4*)(message_bond + (size_t)ab[j] * H + c4 * 4);
    s.x += v.x; s.y += v.y; s.z += v.z; s.w += v.w;
    mx.x = fmaxf(mx.x, v.x); mx.y = fmaxf(mx.y, v.y);
    mx.z = fmaxf(mx.z, v.z); mx.w = fmaxf(mx.w, v.w);
  }
  float4* o = (float4*)(out + (size_t)a * H + c4 * 4);
  float4 r;
  r.x = s.x * mx.x; r.y = s.y * mx.y; r.z = s.z * mx.z; r.w = s.w * mx.w;
  if (UPDATE) {
    float4 c = *o;
    r.x += c.x; r.y += c.y; r.z += c.z; r.w += c.w;
  }
  *o = r;
}

// ======================= misc elementwise =======================
__global__ __launch_bounds__(256) void msg_kernel(
    const float* __restrict__ node, const float* __restrict__ gru_bias,
    float* __restrict__ msg)
{
  int gid = blockIdx.x * 256 + threadIdx.x;
  if (gid >= NAt * H) return;
  int hh = gid % H;
  msg[gid] = fmaxf(node[gid] + gru_bias[hh], 0.f);
}

__global__ __launch_bounds__(256) void h0_kernel(
    const float* __restrict__ node, float* __restrict__ h0)
{
  int gid = blockIdx.x * 256 + threadIdx.x;
  if (gid >= NM * H) return;
  int m = gid / H;
  int hh = gid - m * H;
  const float* base = node + ((size_t)(1 + m * APM)) * H + hh;
  float mx = base[0];
  for (int t = 1; t < APM; t++) mx = fmaxf(mx, base[(size_t)t * H]);
  h0[gid] = mx;
}

__global__ __launch_bounds__(256) void row0_kernel(
    const float* __restrict__ msg, float* __restrict__ message)
{
  int gid = blockIdx.x * 256 + threadIdx.x;
  if (gid >= 2 * H) return;
  message[gid] = msg[gid % H];
}

__global__ __launch_bounds__(256) void mean_kernel(
    const float* __restrict__ ah, float* __restrict__ out)
{
  int gid = blockIdx.x * 256 + threadIdx.x;
  if (gid >= NM * H) return;
  int m = gid / H;
  int hh = gid - m * H;
  const float* base = ah + ((size_t)(1 + m * APM)) * H + hh;
  float s = 0.f;
#pragma unroll 8
  for (int t = 0; t < APM; t++) s += base[(size_t)t * H];
  out[gid] = s * (1.f / APM);
}

// ======================= GRU: block-independent, all 65 steps, ONE launch =======================
// r25 = EXACT r23 (proven 786us GRU / 2051us total — session best).
// Ladder summary: 1 gate/thread = 1365us (LDS h-read bound), 2 gates/thread
// = 786us (h-reads shared across 2 gates), 4 gates/thread = 1622us (needs
// ~110 VGPR; allocator caps at 64 -> register-starved serialization, r24).
// 2 gates/thread at 36 VGPR is the optimum this toolchain's register policy
// admits. 256 blocks (2 mols x dir) x 512 thr; __syncthreads only.
__global__ __launch_bounds__(512) void gru_fused_kernel(
    const float* __restrict__ xg_f, const float* __restrict__ xg_b,
    const float* __restrict__ wq_f, const float* __restrict__ wq_b,
    const float* __restrict__ b_hh_f, const float* __restrict__ b_hh_b,
    const float* __restrict__ h0,
    float* __restrict__ message) // [NAt][600]
{
  __shared__ __attribute__((aligned(16))) float h_lds[2][2 * H];
  __shared__ __attribute__((aligned(16))) float g_lds[2 * H3];
  const int tid = threadIdx.x;
  const int b = blockIdx.x;
  const int mg = b & 127;
  const int dir = b >> 7;
  const int mol0 = mg * 2;
  const float* xg = dir ? xg_b : xg_f;
  const float4* wq = (const float4*)(dir ? wq_b : wq_f);  // [75][900] float4
  const float* bhh = dir ? b_hh_b : b_hh_f;

  for (int s = 0; s <= 64; s++) {
    float* hl_w = h_lds[s & 1];
    const float* hl_r = h_lds[(s ^ 1) & 1];
    int t_prev = 0;
    if (s > 0) t_prev = dir ? (64 - s) : (s - 1);

    // phase 1: h(s) for this block's 2 mols; write message row for t_prev
    for (int i = tid; i < 2 * H; i += 512) {
      int m = i / H;
      int hh = i - m * H;
      int mol = mol0 + m;
      float hc;
      if (s == 0) {
        hc = h0[(size_t)mol * H + hh];
      } else {
        const float* xr = xg + ((size_t)(mol * 64 + t_prev)) * H3;
        float ir = xr[hh], iz = xr[H + hh], inn = xr[2 * H + hh];
        const float* gp = g_lds + m * H3;
        float hr = gp[hh], hz = gp[H + hh], hn = gp[2 * H + hh];
        float hp = hl_r[i];
        float rr = 1.f / (1.f + expf(-(ir + hr)));
        float zz = 1.f / (1.f + expf(-(iz + hz)));
        float nn = tanhf(inn + rr * hn);
        hc = (1.f - zz) * nn + zz * hp;
      }
      hl_w[i] = hc;
      if (s > 0) {
        int row = 1 + mol * 64 + t_prev;
        message[(size_t)row * 600 + dir * H + hh] = hc;
      }
    }
    __syncthreads();
    if (s == 64) break;

    // phase 2: thread t (<450) owns gates g0=t, g1=t+450; 2 mol-accs each.
    if (tid < 450) {
      const int g0 = tid;
      const int g1 = tid + 450;
      float a00 = 0.f, a01 = 0.f;  // gate0 x {mol0, mol1}
      float a10 = 0.f, a11 = 0.f;  // gate1 x {mol0, mol1}
      const float4* hm0 = (const float4*)(hl_w);
      const float4* hm1 = (const float4*)(hl_w + H);
#pragma unroll 2
      for (int c = 0; c < 25; c++) {
        float4 u0 = wq[(size_t)(c * 3 + 0) * H3 + g0];
        float4 u1 = wq[(size_t)(c * 3 + 1) * H3 + g0];
        float4 u2 = wq[(size_t)(c * 3 + 2) * H3 + g0];
        float4 v0 = wq[(size_t)(c * 3 + 0) * H3 + g1];
        float4 v1 = wq[(size_t)(c * 3 + 1) * H3 + g1];
        float4 v2 = wq[(size_t)(c * 3 + 2) * H3 + g1];
        float4 p0 = hm0[c * 3];
        float4 p1 = hm0[c * 3 + 1];
        float4 p2 = hm0[c * 3 + 2];
        float4 q0 = hm1[c * 3];
        float4 q1 = hm1[c * 3 + 1];
        float4 q2 = hm1[c * 3 + 2];
        a00 += u0.x * p0.x + u0.y * p0.y + u0.z * p0.z + u0.w * p0.w
             + u1.x * p1.x + u1.y * p1.y + u1.z * p1.z + u1.w * p1.w
             + u2.x * p2.x + u2.y * p2.y + u2.z * p2.z + u2.w * p2.w;
        a01 += u0.x * q0.x + u0.y * q0.y + u0.z * q0.z + u0.w * q0.w
             + u1.x * q1.x + u1.y * q1.y + u1.z * q1.z + u1.w * q1.w
             + u2.x * q2.x + u2.y * q2.y + u2.z * q2.z + u2.w * q2.w;
        a10 += v0.x * p0.x + v0.y * p0.y + v0.z * p0.z + v0.w * p0.w
             + v1.x * p1.x + v1.y * p1.y + v1.z * p1.z + v1.w * p1.w
             + v2.x * p2.x + v2.y * p2.y + v2.z * p2.z + v2.w * p2.w;
        a11 += v0.x * q0.x + v0.y * q0.y + v0.z * q0.z + v0.w * q0.w
             + v1.x * q1.x + v1.y * q1.y + v1.z * q1.z + v1.w * q1.w
             + v2.x * q2.x + v2.y * q2.y + v2.z * q2.z + v2.w * q2.w;
      }
      const float bb0 = bhh[g0];
      const float bb1 = bhh[g1];
      g_lds[g0] = a00 + bb0;
      g_lds[H3 + g0] = a01 + bb0;
      g_lds[g1] = a10 + bb1;
      g_lds[H3 + g1] = a11 + bb1;
    }
    __syncthreads();
  }
}

// ======================= host =======================
// Base layout 63,898,800 floats = 255.6 MB + pre-split weights 9.2 MB
// + quad-packed w_hh 2.16 MB at tail.
extern "C" void kernel_launch(void* const* d_in, const int* in_sizes, int n_in,
                              void* d_out, int out_size, void* d_ws, size_t ws_size,
                              hipStream_t stream) {
  (void)in_sizes; (void)n_in; (void)out_size; (void)ws_size;
  const float* f_atoms  = (const float*)d_in[0];
  const float* f_bonds  = (const float*)d_in[1];
  const int*   a2b      = (const int*)d_in[2];
  const int*   b2a      = (const int*)d_in[3];
  const int*   b2revb   = (const int*)d_in[4];
  const float* W_i_atom = (const float*)d_in[5];
  const float* W_i_bond = (const float*)d_in[6];
  const float* W_h      = (const float*)d_in[7];
  const float* W_lr     = (const float*)d_in[8];
  const float* W_o      = (const float*)d_in[9];
  const float* b_o      = (const float*)d_in[10];
  const float* gru_bias = (const float*)d_in[11];
  const float* w_ih_f   = (const float*)d_in[12];
  const float* w_hh_f   = (const float*)d_in[13];
  const float* b_ih_f   = (const float*)d_in[14];
  const float* b_hh_f   = (const float*)d_in[15];
  const float* w_ih_b   = (const float*)d_in[16];
  const float* w_hh_b   = (const float*)d_in[17];
  const float* b_ih_b   = (const float*)d_in[18];
  const float* b_hh_b   = (const float*)d_in[19];

  float* ws = (float*)d_ws;
  const size_t SZ_B = (size_t)NBd * H;  // 19,661,100
  const size_t SZ_A = (size_t)NAt * H;  //  4,915,500

  float* ib  = ws;
  float* mb0 = ws + SZ_B;
  float* mb1 = ws + 2 * SZ_B;
  float* ma  = ws + 3 * SZ_B;
  float* xgf     = ib;
  float* message = mb0;
  float* h0      = mb0 + 9831000;
  float* aggb    = mb1;
  float* node    = mb1 + SZ_A;
  float* iat     = mb1 + 2 * SZ_A;
  float* msg     = mb1 + 14745600;
  float* xgb     = mb1;
  float* ah      = ma;

  // pre-split weight region at tail (uint4 granule counts)
  const size_t BASE_FLOATS = 63898800;
  uint4* wsp = (uint4*)(ws + BASE_FLOATS);
  const int G_IA = 5 * 19 * 64;
  const int G_IB = 5 * 19 * 64;
  const int G_WH = 10 * 19 * 64;
  const int G_LR = 29 * 19 * 64;
  const int G_WT = 10 * 57 * 64;
  const int G_WO = 19 * 19 * 64;
  uint4* sp_ia = wsp;
  uint4* sp_ib = sp_ia + 3 * G_IA;
  uint4* sp_wh = sp_ib + 3 * G_IB;
  uint4* sp_lr = sp_wh + 4 * 3 * G_WH;
  uint4* sp_tf = sp_lr + 3 * G_LR;
  uint4* sp_tb = sp_tf + 3 * G_WT;
  uint4* sp_wo = sp_tb + 3 * G_WT;
  // quad-packed w_hh (float) after the split region
  float* wq_f = (float*)(sp_wo + 3 * G_WO);
  float* wq_b = wq_f + (size_t)H * H3;

  dim3 blk(256);
  // all N used here are exact multiples of 19 tiles (300->19, 912->57)
  auto gg3 = [](int M, int NT) {
    return dim3((unsigned)(NT / 19), (unsigned)((M + 63) / 64));
  };
  auto pg = [](int gran) { return dim3((unsigned)((gran + 255) / 256)); };
  const int gA4 = (int)((NAt * 75 + 255) / 256);
  const int gAe = (int)((SZ_A + 255) / 256);
  const int gWT = (int)((H * H3 + 255) / 256);

  // ---- weight prep ----
  prep_split_kernel<false><<<pg(G_IA), blk, 0, stream>>>(W_i_atom, sp_ia, 133, 300, 300, 5, 19);
  prep_split_kernel<false><<<pg(G_IB), blk, 0, stream>>>(W_i_bond, sp_ib, 147, 300, 300, 5, 19);
  for (int d = 0; d < 4; d++)
    prep_split_kernel<false><<<pg(G_WH), blk, 0, stream>>>(
        W_h + (size_t)d * H * H, sp_wh + (size_t)d * 3 * G_WH, 300, 300, 300, 10, 19);
  prep_split_kernel<false><<<pg(G_LR), blk, 0, stream>>>(W_lr, sp_lr, 900, 300, 300, 29, 19);
  prep_split_kernel<true><<<pg(G_WT), blk, 0, stream>>>(w_ih_f, sp_tf, 300, 900, 300, 10, 57);
  prep_split_kernel<true><<<pg(G_WT), blk, 0, stream>>>(w_ih_b, sp_tb, 300, 900, 300, 10, 57);
  prep_split_kernel<false><<<pg(G_WO), blk, 0, stream>>>(W_o, sp_wo, 600, 300, 300, 19, 19);
  prep_wq_kernel<<<gWT, blk, 0, stream>>>(w_hh_f, wq_f);
  prep_wq_kernel<<<gWT, blk, 0, stream>>>(w_hh_b, wq_b);

  // ma = relu(f_atoms @ W_i_atom)
  gemm_mfma3<false,false,true,false,false,false,false><<<gg3(NAt, 19), blk, 0, stream>>>(
      f_atoms, nullptr, nullptr, nullptr, nullptr, sp_ia, ma, nullptr, nullptr, nullptr,
      NAt, H, 133, 133, H, 5, 19);
  // ib = relu(f_bonds @ W_i_bond); mb0 = copy
  gemm_mfma3<false,false,true,false,false,true,false><<<gg3(NBd, 19), blk, 0, stream>>>(
      f_bonds, nullptr, nullptr, nullptr, nullptr, sp_ib, ib, mb0, nullptr, nullptr,
      NBd, H, 147, 147, H, 5, 19);

  float* mbp[2] = {mb0, mb1};
  int cur = 0;
  for (int d = 0; d < 4; d++) {
    agg_kernel<true><<<gA4, blk, 0, stream>>>(mbp[cur], a2b, ma);
    gemm_mfma3<true,false,true,true,false,false,true><<<gg3(NBd, 19), blk, 0, stream>>>(
        ma, mbp[cur], nullptr, b2a, b2revb, sp_wh + (size_t)d * 3 * G_WH,
        mbp[1 - cur], nullptr, ib, nullptr, NBd, H, H, H, H, 10, 19);
    cur ^= 1;
  }
  agg_kernel<false><<<gA4, blk, 0, stream>>>(mb0, a2b, aggb);

  gemm_mfma3<false,false,true,false,false,false,false><<<gg3(NAt, 19), blk, 0, stream>>>(
      f_atoms, nullptr, nullptr, nullptr, nullptr, sp_ia, iat, nullptr, nullptr, nullptr,
      NAt, H, 133, 133, H, 5, 19);
  gemm_mfma3<false,false,false,false,true,false,false><<<gg3(NAt, 19), blk, 0, stream>>>(
      aggb, ma, iat, nullptr, nullptr, sp_lr, node, nullptr, nullptr, nullptr,
      NAt, H, 900, H, H, 29, 19);

  h0_kernel<<<(NM * H + 255) / 256, blk, 0, stream>>>(node, h0);
  msg_kernel<<<gAe, blk, 0, stream>>>(node, gru_bias, msg);

  gemm_mfma3<false,true,false,false,false,false,true><<<gg3(16384, 57), blk, 0, stream>>>(
      msg + H, nullptr, nullptr, nullptr, nullptr, sp_tf, xgf, nullptr, nullptr, b_ih_f,
      16384, H3, H, H, H3, 10, 57);
  gemm_mfma3<false,true,false,false,false,false,true><<<gg3(16384, 57), blk, 0, stream>>>(
      msg + H, nullptr, nullptr, nullptr, nullptr, sp_tb, xgb, nullptr, nullptr, b_ih_b,
      16384, H3, H, H, H3, 10, 57);

  // all 65 GRU steps: one launch, 256 independent blocks, 2 gates/thread
  gru_fused_kernel<<<dim3(256), dim3(512), 0, stream>>>(
      xgf, xgb, wq_f, wq_b, b_hh_f, b_hh_b, h0, message);

  row0_kernel<<<3, blk, 0, stream>>>(msg, message);

  gemm_mfma3<false,true,true,false,false,false,true><<<gg3(NAt, 19), blk, 0, stream>>>(
      message, nullptr, nullptr, nullptr, nullptr, sp_wo, ah, nullptr, nullptr, b_o,
      NAt, H, 600, 600, H, 19, 19);
  mean_kernel<<<(NM * H + 255) / 256, blk, 0, stream>>>(ah, (float*)d_out);
}